// Round 1
// baseline (116.897 us; speedup 1.0000x reference)
//
#include <hip/hip_runtime.h>
#include <hip/hip_bf16.h>
#include <stdint.h>

// out = X @ Bbig + bias, where X = (32768 x 1024) fp32 (real||imag),
// Bbig (1024x1024) assembled from TT factors:
//   n<512  (real out o=n):   B[k][n] = Wr[n][k]      (k<512),  -Wi[n][k-512]  (k>=512)
//   n>=512 (imag out o=n-512): B[k][n] = Wi[o][k]    (k<512),   Wr[o][k-512]  (k>=512)
// W_X[o][i] = sum_c G1_X[0][o>>4][c][i>>4] * G2_X[c][o&15][0][i&15]

typedef _Float16 half8 __attribute__((ext_vector_type(8)));
typedef _Float16 half4v __attribute__((ext_vector_type(4)));
typedef float f32x4 __attribute__((ext_vector_type(4)));

typedef __attribute__((address_space(3))) void* lds_ptr_t;
typedef const __attribute__((address_space(1))) void* gbl_ptr_t;

__device__ __forceinline__ void gload_lds16(const void* g, void* s) {
  // HW semantics: lane l's 16B land at (wave-uniform) s + l*16
  __builtin_amdgcn_global_load_lds((gbl_ptr_t)g, (lds_ptr_t)s, 16, 0, 0);
}

// ---------------- Kernel 1: build Bt[n][k] = Bbig[k][n] in fp16 ----------------
__global__ void build_bt(const float* __restrict__ G1R, const float* __restrict__ G2R,
                         const float* __restrict__ G1I, const float* __restrict__ G2I,
                         _Float16* __restrict__ BT) {
  int idx = blockIdx.x * 256 + threadIdx.x;  // 0 .. 1M-1
  int n = idx >> 10, k = idx & 1023;
  int o = n & 511, i = k & 511;
  bool imagOut = n >= 512, kHi = k >= 512;
  const float* G1;
  const float* G2;
  float sign = 1.0f;
  if (imagOut == kHi) { G1 = G1R; G2 = G2R; }        // W_real
  else { G1 = G1I; G2 = G2I; if (!imagOut) sign = -1.0f; }  // +/- W_imag
  int b = o >> 4, e = o & 15, d = i >> 4, g = i & 15;
  float w = 0.0f;
#pragma unroll
  for (int c = 0; c < 4; ++c)
    w += G1[b * 128 + c * 32 + d] * G2[c * 256 + e * 16 + g];
  BT[idx] = (_Float16)(sign * w);
}

// ---------------- Kernel 2: GEMM M=32768 K=1024 N=1024 ----------------
// 128x128 tile, BK=32, 256 threads (4 waves, 2x2), 16x16x32 f16 MFMA, 4x4 frags/wave.
__global__ __launch_bounds__(256, 2) void tt_gemm(
    const float* __restrict__ A,       // 32768 x 1024 fp32
    const _Float16* __restrict__ BT,   // 1024 x 1024 fp16 (n-major)
    const float* __restrict__ bias_r, const float* __restrict__ bias_i,
    float* __restrict__ C) {           // 32768 x 1024 fp32
  __shared__ __align__(16) _Float16 Als[128 * 32];
  __shared__ __align__(16) _Float16 Bls[128 * 32];

  const int tid = threadIdx.x;
  const int bid = blockIdx.x;
  // XCD-aware swizzle: 2048 blocks, 8 XCDs -> each XCD gets 256 contiguous ids;
  // n-tile fastest so the 8 blocks sharing an A tile are consecutive on one XCD.
  const int bid2 = (bid & 7) * 256 + (bid >> 3);
  const int mt = bid2 >> 3, nt = bid2 & 7;
  const int row0 = mt * 128, col0 = nt * 128;

  const int lane = tid & 63, wid = tid >> 6;
  const int wm = wid >> 1, wn = wid & 1;       // wave -> 64x64 subtile
  const int lr = lane & 15, lq = lane >> 4;

  f32x4 acc[4][4] = {};

  // B staging source geometry (matches gload_lds lane->lds mapping)
  const int brow_base = wid * 32 + (lane >> 2);
  const int bk = (lane & 3) * 8;

  const float* Abase = A + (size_t)row0 * 1024;

  for (int kt = 0; kt < 32; ++kt) {
    const int k0 = kt * 32;
    // (1) issue A global loads (fp32) into regs
    float4 va[4];
#pragma unroll
    for (int i = 0; i < 4; ++i) {
      int fid = i * 256 + tid;
      int ar = fid >> 3, aq = fid & 7;
      va[i] = *(const float4*)(Abase + (size_t)ar * 1024 + k0 + aq * 4);
    }
    __syncthreads();  // previous iteration's MFMA reads done
    // (2a) convert + write A tile to LDS
#pragma unroll
    for (int i = 0; i < 4; ++i) {
      int fid = i * 256 + tid;
      int ar = fid >> 3, aq = fid & 7;
      half4v h = { (_Float16)va[i].x, (_Float16)va[i].y,
                   (_Float16)va[i].z, (_Float16)va[i].w };
      *(half4v*)&Als[ar * 32 + aq * 4] = h;
    }
    // (2b) B tile via async global->LDS (16B/lane, 1KB/wave-call, 8KB total)
#pragma unroll
    for (int j = 0; j < 2; ++j) {
      gload_lds16(BT + (size_t)(col0 + brow_base + j * 16) * 1024 + k0 + bk,
                  (char*)Bls + (wid * 2 + j) * 1024);
    }
    __syncthreads();  // drains vmcnt (B) + lgkmcnt (A writes)
    // (3) 16 MFMAs
    half8 af[4], bf[4];
#pragma unroll
    for (int m = 0; m < 4; ++m)
      af[m] = *(const half8*)&Als[(wm * 64 + m * 16 + lr) * 32 + lq * 8];
#pragma unroll
    for (int n = 0; n < 4; ++n)
      bf[n] = *(const half8*)&Bls[(wn * 64 + n * 16 + lr) * 32 + lq * 8];
#pragma unroll
    for (int m = 0; m < 4; ++m)
#pragma unroll
      for (int n = 0; n < 4; ++n)
        acc[m][n] = __builtin_amdgcn_mfma_f32_16x16x32_f16(af[m], bf[n], acc[m][n], 0, 0, 0);
  }

  // Epilogue: C/D layout col=lane&15, row=(lane>>4)*4+reg
#pragma unroll
  for (int n = 0; n < 4; ++n) {
    int col = col0 + wn * 64 + n * 16 + lr;
    float bias = (col < 512) ? bias_r[col] : bias_i[col - 512];
#pragma unroll
    for (int m = 0; m < 4; ++m) {
      int r0 = row0 + wm * 64 + m * 16 + lq * 4;
#pragma unroll
      for (int r = 0; r < 4; ++r)
        C[(size_t)(r0 + r) * 1024 + col] = acc[m][n][r] + bias;
    }
  }
}

extern "C" void kernel_launch(void* const* d_in, const int* in_sizes, int n_in,
                              void* d_out, int out_size, void* d_ws, size_t ws_size,
                              hipStream_t stream) {
  const float* x   = (const float*)d_in[0];
  const float* G1R = (const float*)d_in[1];
  const float* G2R = (const float*)d_in[2];
  const float* G1I = (const float*)d_in[3];
  const float* G2I = (const float*)d_in[4];
  const float* br  = (const float*)d_in[5];
  const float* bi  = (const float*)d_in[6];
  float* out = (float*)d_out;
  _Float16* BT = (_Float16*)d_ws;  // 1024*1024*2B = 2 MB scratch

  build_bt<<<4096, 256, 0, stream>>>(G1R, G2R, G1I, G2I, BT);
  tt_gemm<<<2048, 256, 0, stream>>>(x, BT, br, bi, out);
}